// Round 15
// baseline (146.571 us; speedup 1.0000x reference)
//
#include <hip/hip_runtime.h>
#include <hip/hip_bf16.h>
#include <math.h>

#define NN 50000
#define EE 800000
#define DD 64
#define NSLOPE 0.2f
#define NBUCK 196          // bucket = dst >> 8 (256 dsts per bucket)
#define CAP 4608           // bucket capacity (mean 4082, +8 sigma)
#define CHUNK 2048         // edges per bin block
#define BINB ((EE + CHUNK - 1) / CHUNK)   // 391
#define WHB 782            // wh blocks; 4 waves x 4 rows each per iter

__device__ __forceinline__ float leaky(float s) { return s > 0.f ? s : NSLOPE * s; }

// ---- K1: blocks [0,BINB) bin edges to buckets ; [BINB,BINB+WHB) Wh GEMM -----
// bin: 12 KB LDS, few VGPR. wh: 20 KB LDS, ~110 VGPR (4-row register tile).
__global__ void __launch_bounds__(256) bin_wh_kernel(
    const int* __restrict__ ei, unsigned int* __restrict__ gbuf,
    int* __restrict__ gCursor,
    const float* __restrict__ x, const float* __restrict__ W,
    const float* __restrict__ bias, float* __restrict__ Wh) {
    __shared__ __align__(16) char smem[20480];
    int tid = threadIdx.x;

    if (blockIdx.x < BINB) {
        // ---------------- bin part ----------------
        int* cnt  = (int*)smem;
        int* excl = cnt + 256;
        int* cur  = cnt + 512;
        int* base = cnt + 768;
        unsigned int* pairs = (unsigned int*)(smem + 4096);   // 8 KB
        int start = blockIdx.x * CHUNK;
        int nedge = min(CHUNK, EE - start);
        cnt[tid] = 0; cur[tid] = 0;
        __syncthreads();
        for (int j = 0; j < CHUNK / 256; ++j) {
            int i = start + tid + j * 256;
            if (i < EE) atomicAdd(&cnt[((unsigned int)ei[EE + i]) >> 8], 1);
        }
        __syncthreads();
        int v = cnt[tid];
        excl[tid] = v; __syncthreads();
        for (int o = 1; o < 256; o <<= 1) {
            int t = (tid >= o) ? excl[tid - o] : 0;
            __syncthreads();
            excl[tid] += t;
            __syncthreads();
        }
        int ex = excl[tid] - v;
        __syncthreads();
        excl[tid] = ex;
        __syncthreads();
        for (int j = 0; j < CHUNK / 256; ++j) {
            int i = start + tid + j * 256;
            if (i < EE) {
                unsigned int src = (unsigned int)ei[i];
                unsigned int dst = (unsigned int)ei[EE + i];
                int bk = dst >> 8;
                int r = atomicAdd(&cur[bk], 1);
                pairs[excl[bk] + r] = (dst << 16) | src;
            }
        }
        if (tid < NBUCK) base[tid] = atomicAdd(&gCursor[tid], cnt[tid]);
        __syncthreads();
        for (int i = tid; i < nedge; i += 256) {
            unsigned int p = pairs[i];
            int bk = p >> 24;
            gbuf[(size_t)bk * CAP + base[bk] + (i - excl[bk])] = p;
        }
        return;
    }

    // ---------------- wh part: 4 rows per wave-iteration (validated) --------
    int bid = blockIdx.x - BINB;
    float4* Wl = (float4*)smem;                         // 16 KB, swizzled
    float4 (*xr)[4][16] = (float4 (*)[4][16])(smem + 16384);  // [wave][row][quad]
    const float4* W4 = (const float4*)W;
    const float4* x4 = (const float4*)x;
    for (int i = tid; i < 1024; i += 256) {
        int c = i >> 4, k4 = i & 15;
        Wl[c * 16 + (k4 ^ (c & 15))] = W4[i];
    }
    __syncthreads();
    int wv = tid >> 6, lane = tid & 63;
    int c = lane;
    float4 wreg[16];
#pragma unroll
    for (int k4 = 0; k4 < 16; ++k4) wreg[k4] = Wl[c * 16 + (k4 ^ (c & 15))];
    float bv = bias[c];
    int l16 = lane >> 4, q = lane & 15;
    for (int rowbase = (bid * 4 + wv) * 4; rowbase < NN; rowbase += WHB * 16) {
        xr[wv][l16][q] = x4[(size_t)(rowbase + l16) * 16 + q];
        float acc0 = bv, acc1 = bv, acc2 = bv, acc3 = bv;
#pragma unroll
        for (int k4 = 0; k4 < 16; ++k4) {
            float4 w  = wreg[k4];
            float4 q0 = xr[wv][0][k4];
            float4 q1 = xr[wv][1][k4];
            float4 q2 = xr[wv][2][k4];
            float4 q3 = xr[wv][3][k4];
            acc0 += w.x * q0.x + w.y * q0.y + w.z * q0.z + w.w * q0.w;
            acc1 += w.x * q1.x + w.y * q1.y + w.z * q1.z + w.w * q1.w;
            acc2 += w.x * q2.x + w.y * q2.y + w.z * q2.z + w.w * q2.w;
            acc3 += w.x * q3.x + w.y * q3.y + w.z * q3.z + w.w * q3.w;
        }
        Wh[(size_t)(rowbase + 0) * DD + c] = acc0;
        Wh[(size_t)(rowbase + 1) * DD + c] = acc1;
        Wh[(size_t)(rowbase + 2) * DD + c] = acc2;
        Wh[(size_t)(rowbase + 3) * DD + c] = acc3;
    }
}

// ---- K2: per-bucket CSR build (inline bucket scan; L2-local scatter) --------
__global__ void __launch_bounds__(256) csr_kernel(
    const unsigned int* __restrict__ gbuf, const int* __restrict__ gCursor,
    int* __restrict__ off, unsigned short* __restrict__ csr) {
    __shared__ int s[256];
    __shared__ int hist[256];
    __shared__ int excl[256];
    __shared__ int cur[256];
    int tid = threadIdx.x;
    int k = blockIdx.x;
    int v = (tid < NBUCK) ? gCursor[tid] : 0;
    s[tid] = v; __syncthreads();
    for (int o = 1; o < 256; o <<= 1) {
        int t = (tid >= o) ? s[tid - o] : 0;
        __syncthreads();
        s[tid] += t;
        __syncthreads();
    }
    int base_k = (k == 0) ? 0 : s[k - 1];
    int cnt = s[k] - base_k;
    const unsigned int* bp = gbuf + (size_t)k * CAP;
    hist[tid] = 0; cur[tid] = 0;
    __syncthreads();
    for (int i = tid; i < cnt; i += 256)
        atomicAdd(&hist[(bp[i] >> 16) & 255], 1);
    __syncthreads();
    int hv = hist[tid];
    excl[tid] = hv; __syncthreads();
    for (int o = 1; o < 256; o <<= 1) {
        int t = (tid >= o) ? excl[tid - o] : 0;
        __syncthreads();
        excl[tid] += t;
        __syncthreads();
    }
    int hex = excl[tid] - hv;
    __syncthreads();
    excl[tid] = hex;
    __syncthreads();
    int dst = k * 256 + tid;
    if (dst < NN) off[dst] = base_k + hex;
    if (k == 0 && tid == 0) off[NN] = EE;
    for (int i = tid; i < cnt; i += 256) {
        unsigned int p = bp[i];
        int local = (p >> 16) & 255;
        int slot = base_k + excl[local] + atomicAdd(&cur[local], 1);
        csr[slot] = (unsigned short)(p & 0xffffu);
    }
}

// ---- K3: fused gather + softmax + sigmoid; branch-free clamped prefetch ----
__global__ void __launch_bounds__(256) fused_kernel(
    const float4* __restrict__ Wh4, const float4* __restrict__ a4,
    const int* __restrict__ off, const unsigned short* __restrict__ csr,
    float4* __restrict__ out4) {
    int wave = threadIdx.x >> 6, lane = threadIdx.x & 63;
    int node = blockIdx.x * 4 + wave;
    int b = lane >> 4, f4 = lane & 15;
    float4 av  = a4[f4];
    float4 whi = Wh4[(size_t)node * 16 + f4];
    int beg = off[node], end = off[node + 1];
    float den = 0.f;
    float4 acc = make_float4(0.f, 0.f, 0.f, 0.f);
    if (beg < end) {
        int last = end - 1;
        int i0 = min(beg + b, last);
        int i1 = min(beg + 4 + b, last);
        float4 p0 = Wh4[(size_t)csr[i0] * 16 + f4];
        float4 p1 = Wh4[(size_t)csr[i1] * 16 + f4];
        for (int base = beg; base < end; base += 4) {
            float4 whs = p0;
            p0 = p1;
            int ni = min(base + 8 + b, last);          // clamped, always valid
            p1 = Wh4[(size_t)csr[ni] * 16 + f4];
            float t = av.x * leaky(whi.x + whs.x) + av.y * leaky(whi.y + whs.y)
                    + av.z * leaky(whi.z + whs.z) + av.w * leaky(whi.w + whs.w);
            t += __shfl_xor(t, 1, 64);
            t += __shfl_xor(t, 2, 64);
            t += __shfl_xor(t, 4, 64);
            t += __shfl_xor(t, 8, 64);
            float ex = (base + b < end) ? __expf(t) : 0.f;
            den += ex;
            acc.x += ex * whs.x; acc.y += ex * whs.y;
            acc.z += ex * whs.z; acc.w += ex * whs.w;
        }
    }
    acc.x += __shfl_xor(acc.x, 16, 64); acc.y += __shfl_xor(acc.y, 16, 64);
    acc.z += __shfl_xor(acc.z, 16, 64); acc.w += __shfl_xor(acc.w, 16, 64);
    den   += __shfl_xor(den,   16, 64);
    acc.x += __shfl_xor(acc.x, 32, 64); acc.y += __shfl_xor(acc.y, 32, 64);
    acc.z += __shfl_xor(acc.z, 32, 64); acc.w += __shfl_xor(acc.w, 32, 64);
    den   += __shfl_xor(den,   32, 64);
    if (b == 0) {
        float id = 1.f / fmaxf(den, 1e-9f);
        float4 o;
        o.x = 1.f / (1.f + __expf(-acc.x * id));
        o.y = 1.f / (1.f + __expf(-acc.y * id));
        o.z = 1.f / (1.f + __expf(-acc.z * id));
        o.w = 1.f / (1.f + __expf(-acc.w * id));
        out4[(size_t)node * 16 + f4] = o;
    }
}

extern "C" void kernel_launch(void* const* d_in, const int* in_sizes, int n_in,
                              void* d_out, int out_size, void* d_ws, size_t ws_size,
                              hipStream_t stream) {
    const float* x = (const float*)d_in[0];
    const float* W = (const float*)d_in[1];
    const float* b = (const float*)d_in[2];
    const float* a = (const float*)d_in[3];
    const int*   ei = (const int*)d_in[4];
    float* out = (float*)d_out;

    char* ws = (char*)d_ws;
    float*          Wh      = (float*)(ws);                    // 12,800,000 B
    int*            gCursor = (int*)(ws + 12800000);           // 1,024 B
    int*            off     = (int*)(ws + 12801024);           // 200,004 B
    unsigned int*   gbuf    = (unsigned int*)(ws + 13001216);  // 3,612,672 B
    unsigned short* csr     = (unsigned short*)(ws + 16613888);// 1,600,000 B

    hipMemsetAsync(gCursor, 0, 1024, stream);
    bin_wh_kernel<<<BINB + WHB, 256, 0, stream>>>(ei, gbuf, gCursor, x, W, b, Wh);
    csr_kernel<<<NBUCK, 256, 0, stream>>>(gbuf, gCursor, off, csr);
    fused_kernel<<<NN / 4, 256, 0, stream>>>((const float4*)Wh, (const float4*)a,
                                             off, csr, (float4*)out);
}

// Round 16
// 139.133 us; speedup vs baseline: 1.0535x; 1.0535x over previous
//
#include <hip/hip_runtime.h>
#include <hip/hip_bf16.h>
#include <math.h>

#define NN 50000
#define EE 800000
#define DD 64
#define NSLOPE 0.2f
#define NBUCK 196          // bucket = dst >> 8 (256 dsts per bucket)
#define CAP 4608           // bucket capacity (mean 4082, +8 sigma)
#define CHUNK 2048         // edges per bin block (391 blocks)
#define BINB ((EE + CHUNK - 1) / CHUNK)   // 391
#define WHB 782            // wh blocks; 4 waves x 4 rows each per iter

__device__ __forceinline__ float leaky(float s) { return s > 0.f ? s : NSLOPE * s; }
__device__ __forceinline__ float b2f(unsigned short u) {
    return __uint_as_float(((unsigned)u) << 16);
}
__device__ __forceinline__ unsigned short f2b(float f) {   // RNE bf16
    unsigned b = __float_as_uint(f);
    return (unsigned short)((b + 0x7fffu + ((b >> 16) & 1u)) >> 16);
}

// ---- K1: bin edges into coarse buckets (4B packed pairs, coalesced flush) ---
__global__ void __launch_bounds__(256) bin_kernel(
    const int* __restrict__ ei, unsigned int* __restrict__ gbuf,
    int* __restrict__ gCursor) {
    __shared__ int cnt[256];
    __shared__ int excl[256];
    __shared__ int cur[256];
    __shared__ int base[256];
    __shared__ unsigned int pairs[CHUNK];
    int tid = threadIdx.x;
    int start = blockIdx.x * CHUNK;
    int nedge = min(CHUNK, EE - start);
    cnt[tid] = 0; cur[tid] = 0;
    __syncthreads();
    for (int j = 0; j < CHUNK / 256; ++j) {
        int i = start + tid + j * 256;
        if (i < EE) atomicAdd(&cnt[((unsigned int)ei[EE + i]) >> 8], 1);
    }
    __syncthreads();
    int v = cnt[tid];
    excl[tid] = v; __syncthreads();
    for (int o = 1; o < 256; o <<= 1) {
        int t = (tid >= o) ? excl[tid - o] : 0;
        __syncthreads();
        excl[tid] += t;
        __syncthreads();
    }
    int ex = excl[tid] - v;
    __syncthreads();
    excl[tid] = ex;
    __syncthreads();
    for (int j = 0; j < CHUNK / 256; ++j) {
        int i = start + tid + j * 256;
        if (i < EE) {
            unsigned int src = (unsigned int)ei[i];
            unsigned int dst = (unsigned int)ei[EE + i];
            int b = dst >> 8;
            int r = atomicAdd(&cur[b], 1);
            pairs[excl[b] + r] = (dst << 16) | src;
        }
    }
    if (tid < NBUCK) base[tid] = atomicAdd(&gCursor[tid], cnt[tid]);
    __syncthreads();
    for (int i = tid; i < nedge; i += 256) {
        unsigned int p = pairs[i];
        int b = p >> 24;
        gbuf[(size_t)b * CAP + base[b] + (i - excl[b])] = p;
    }
}

// ---- K2: blocks < NBUCK: inline bucket-scan + per-bucket CSR build
//          blocks >= NBUCK: Wh = x @ W^T + b (4-row tile; writes f32 + bf16)
__global__ void __launch_bounds__(256) csr_wh_kernel(
    const unsigned int* __restrict__ gbuf, const int* __restrict__ gCursor,
    int* __restrict__ off, unsigned short* __restrict__ csr,
    const float* __restrict__ x, const float* __restrict__ W,
    const float* __restrict__ bias, float* __restrict__ Wh,
    unsigned short* __restrict__ Whb) {
    __shared__ __align__(16) char smem[20480];
    int tid = threadIdx.x;

    if (blockIdx.x < NBUCK) {
        int* s    = (int*)smem;
        int* hist = s + 256;
        int* excl = s + 512;
        int* cur  = s + 768;
        int k = blockIdx.x;
        int v = (tid < NBUCK) ? gCursor[tid] : 0;
        s[tid] = v; __syncthreads();
        for (int o = 1; o < 256; o <<= 1) {
            int t = (tid >= o) ? s[tid - o] : 0;
            __syncthreads();
            s[tid] += t;
            __syncthreads();
        }
        int base_k = (k == 0) ? 0 : s[k - 1];
        int cnt = s[k] - base_k;
        const unsigned int* bp = gbuf + (size_t)k * CAP;
        hist[tid] = 0; cur[tid] = 0;
        __syncthreads();
        for (int i = tid; i < cnt; i += 256)
            atomicAdd(&hist[(bp[i] >> 16) & 255], 1);
        __syncthreads();
        int hv = hist[tid];
        excl[tid] = hv; __syncthreads();
        for (int o = 1; o < 256; o <<= 1) {
            int t = (tid >= o) ? excl[tid - o] : 0;
            __syncthreads();
            excl[tid] += t;
            __syncthreads();
        }
        int hex = excl[tid] - hv;
        __syncthreads();
        excl[tid] = hex;
        __syncthreads();
        int dst = k * 256 + tid;
        if (dst < NN) off[dst] = base_k + hex;
        if (k == 0 && tid == 0) off[NN] = EE;
        for (int i = tid; i < cnt; i += 256) {
            unsigned int p = bp[i];
            int local = (p >> 16) & 255;
            int slot = base_k + excl[local] + atomicAdd(&cur[local], 1);
            csr[slot] = (unsigned short)(p & 0xffffu);
        }
        return;
    }

    // ---------------- wh part: 4 rows per wave-iteration ----------------
    int bid = blockIdx.x - NBUCK;
    float4* Wl = (float4*)smem;                         // 16 KB, swizzled
    float4 (*xr)[4][16] = (float4 (*)[4][16])(smem + 16384);
    const float4* W4 = (const float4*)W;
    const float4* x4 = (const float4*)x;
    for (int i = tid; i < 1024; i += 256) {
        int c = i >> 4, k4 = i & 15;
        Wl[c * 16 + (k4 ^ (c & 15))] = W4[i];
    }
    __syncthreads();
    int wv = tid >> 6, lane = tid & 63;
    int c = lane;
    float4 wreg[16];
#pragma unroll
    for (int k4 = 0; k4 < 16; ++k4) wreg[k4] = Wl[c * 16 + (k4 ^ (c & 15))];
    float bv = bias[c];
    int l16 = lane >> 4, q = lane & 15;
    for (int rowbase = (bid * 4 + wv) * 4; rowbase < NN; rowbase += WHB * 16) {
        xr[wv][l16][q] = x4[(size_t)(rowbase + l16) * 16 + q];
        float acc0 = bv, acc1 = bv, acc2 = bv, acc3 = bv;
#pragma unroll
        for (int k4 = 0; k4 < 16; ++k4) {
            float4 w  = wreg[k4];
            float4 q0 = xr[wv][0][k4];
            float4 q1 = xr[wv][1][k4];
            float4 q2 = xr[wv][2][k4];
            float4 q3 = xr[wv][3][k4];
            acc0 += w.x * q0.x + w.y * q0.y + w.z * q0.z + w.w * q0.w;
            acc1 += w.x * q1.x + w.y * q1.y + w.z * q1.z + w.w * q1.w;
            acc2 += w.x * q2.x + w.y * q2.y + w.z * q2.z + w.w * q2.w;
            acc3 += w.x * q3.x + w.y * q3.y + w.z * q3.z + w.w * q3.w;
        }
        Wh[(size_t)(rowbase + 0) * DD + c] = acc0;
        Wh[(size_t)(rowbase + 1) * DD + c] = acc1;
        Wh[(size_t)(rowbase + 2) * DD + c] = acc2;
        Wh[(size_t)(rowbase + 3) * DD + c] = acc3;
        Whb[(size_t)(rowbase + 0) * DD + c] = f2b(acc0);
        Whb[(size_t)(rowbase + 1) * DD + c] = f2b(acc1);
        Whb[(size_t)(rowbase + 2) * DD + c] = f2b(acc2);
        Whb[(size_t)(rowbase + 3) * DD + c] = f2b(acc3);
    }
}

// ---- K3: fused gather (bf16 rows) + softmax + sigmoid; clamped prefetch ----
__global__ void __launch_bounds__(256) fused_kernel(
    const float4* __restrict__ Wh4, const unsigned short* __restrict__ Whb,
    const float4* __restrict__ a4, const int* __restrict__ off,
    const unsigned short* __restrict__ csr, float4* __restrict__ out4) {
    int wave = threadIdx.x >> 6, lane = threadIdx.x & 63;
    int node = blockIdx.x * 4 + wave;
    int b = lane >> 4, f4 = lane & 15;
    float4 av  = a4[f4];
    float4 whi = Wh4[(size_t)node * 16 + f4];     // dst row in f32
    int beg = off[node], end = off[node + 1];
    float den = 0.f;
    float4 acc = make_float4(0.f, 0.f, 0.f, 0.f);
    if (beg < end) {
        int last = end - 1;
        int i0 = min(beg + b, last);
        int i1 = min(beg + 4 + b, last);
        ushort4 p0 = *(const ushort4*)(Whb + (size_t)csr[i0] * DD + f4 * 4);
        ushort4 p1 = *(const ushort4*)(Whb + (size_t)csr[i1] * DD + f4 * 4);
        for (int base = beg; base < end; base += 4) {
            ushort4 u = p0;
            p0 = p1;
            int ni = min(base + 8 + b, last);      // clamped, always valid
            p1 = *(const ushort4*)(Whb + (size_t)csr[ni] * DD + f4 * 4);
            float4 whs = make_float4(b2f(u.x), b2f(u.y), b2f(u.z), b2f(u.w));
            float t = av.x * leaky(whi.x + whs.x) + av.y * leaky(whi.y + whs.y)
                    + av.z * leaky(whi.z + whs.z) + av.w * leaky(whi.w + whs.w);
            t += __shfl_xor(t, 1, 64);
            t += __shfl_xor(t, 2, 64);
            t += __shfl_xor(t, 4, 64);
            t += __shfl_xor(t, 8, 64);
            float ex = (base + b < end) ? __expf(t) : 0.f;
            den += ex;
            acc.x += ex * whs.x; acc.y += ex * whs.y;
            acc.z += ex * whs.z; acc.w += ex * whs.w;
        }
    }
    acc.x += __shfl_xor(acc.x, 16, 64); acc.y += __shfl_xor(acc.y, 16, 64);
    acc.z += __shfl_xor(acc.z, 16, 64); acc.w += __shfl_xor(acc.w, 16, 64);
    den   += __shfl_xor(den,   16, 64);
    acc.x += __shfl_xor(acc.x, 32, 64); acc.y += __shfl_xor(acc.y, 32, 64);
    acc.z += __shfl_xor(acc.z, 32, 64); acc.w += __shfl_xor(acc.w, 32, 64);
    den   += __shfl_xor(den,   32, 64);
    if (b == 0) {
        float id = 1.f / fmaxf(den, 1e-9f);
        float4 o;
        o.x = 1.f / (1.f + __expf(-acc.x * id));
        o.y = 1.f / (1.f + __expf(-acc.y * id));
        o.z = 1.f / (1.f + __expf(-acc.z * id));
        o.w = 1.f / (1.f + __expf(-acc.w * id));
        out4[(size_t)node * 16 + f4] = o;
    }
}

extern "C" void kernel_launch(void* const* d_in, const int* in_sizes, int n_in,
                              void* d_out, int out_size, void* d_ws, size_t ws_size,
                              hipStream_t stream) {
    const float* x = (const float*)d_in[0];
    const float* W = (const float*)d_in[1];
    const float* b = (const float*)d_in[2];
    const float* a = (const float*)d_in[3];
    const int*   ei = (const int*)d_in[4];
    float* out = (float*)d_out;

    char* ws = (char*)d_ws;
    float*          Wh      = (float*)(ws);                    // 12,800,000 B
    int*            gCursor = (int*)(ws + 12800000);           // 1,024 B
    int*            off     = (int*)(ws + 12801024);           // 200,004 B
    unsigned int*   gbuf    = (unsigned int*)(ws + 13001216);  // 3,612,672 B
    unsigned short* csr     = (unsigned short*)(ws + 16613888);// 1,600,000 B
    unsigned short* Whb     = (unsigned short*)(ws + 18214912);// 6,400,000 B

    hipMemsetAsync(gCursor, 0, 1024, stream);
    bin_kernel<<<BINB, 256, 0, stream>>>(ei, gbuf, gCursor);
    csr_wh_kernel<<<NBUCK + WHB, 256, 0, stream>>>(gbuf, gCursor, off, csr,
                                                   x, W, b, Wh, Whb);
    fused_kernel<<<NN / 4, 256, 0, stream>>>((const float4*)Wh, Whb,
                                             (const float4*)a, off, csr,
                                             (float4*)out);
}

// Round 17
// 131.330 us; speedup vs baseline: 1.1161x; 1.0594x over previous
//
#include <hip/hip_runtime.h>
#include <hip/hip_bf16.h>
#include <math.h>

#define NN 50000
#define EE 800000
#define DD 64
#define NSLOPE 0.2f
#define NBUCK 196          // bucket = dst >> 8 (256 dsts per bucket)
#define CAP 4608           // bucket capacity (mean 4082, +8 sigma)
#define CHUNK 2048         // edges per bin block (391 blocks)
#define BINB ((EE + CHUNK - 1) / CHUNK)   // 391
#define WHB 782            // wh blocks; 4 waves x 4 rows each per iter

__device__ __forceinline__ float leaky(float s) { return s > 0.f ? s : NSLOPE * s; }
__device__ __forceinline__ unsigned short f2b(float f) {   // RNE bf16
    unsigned b = __float_as_uint(f);
    return (unsigned short)((b + 0x7fffu + ((b >> 16) & 1u)) >> 16);
}
__device__ __forceinline__ void unpack2(unsigned u, float& lo, float& hi) {
    lo = __uint_as_float(u << 16);          // low ushort -> f32
    hi = __uint_as_float(u & 0xffff0000u);  // high ushort -> f32
}

// ---- K1: bin edges into coarse buckets (4B packed pairs, coalesced flush) ---
__global__ void __launch_bounds__(256) bin_kernel(
    const int* __restrict__ ei, unsigned int* __restrict__ gbuf,
    int* __restrict__ gCursor) {
    __shared__ int cnt[256];
    __shared__ int excl[256];
    __shared__ int cur[256];
    __shared__ int base[256];
    __shared__ unsigned int pairs[CHUNK];
    int tid = threadIdx.x;
    int start = blockIdx.x * CHUNK;
    int nedge = min(CHUNK, EE - start);
    cnt[tid] = 0; cur[tid] = 0;
    __syncthreads();
    for (int j = 0; j < CHUNK / 256; ++j) {
        int i = start + tid + j * 256;
        if (i < EE) atomicAdd(&cnt[((unsigned int)ei[EE + i]) >> 8], 1);
    }
    __syncthreads();
    int v = cnt[tid];
    excl[tid] = v; __syncthreads();
    for (int o = 1; o < 256; o <<= 1) {
        int t = (tid >= o) ? excl[tid - o] : 0;
        __syncthreads();
        excl[tid] += t;
        __syncthreads();
    }
    int ex = excl[tid] - v;
    __syncthreads();
    excl[tid] = ex;
    __syncthreads();
    for (int j = 0; j < CHUNK / 256; ++j) {
        int i = start + tid + j * 256;
        if (i < EE) {
            unsigned int src = (unsigned int)ei[i];
            unsigned int dst = (unsigned int)ei[EE + i];
            int b = dst >> 8;
            int r = atomicAdd(&cur[b], 1);
            pairs[excl[b] + r] = (dst << 16) | src;
        }
    }
    if (tid < NBUCK) base[tid] = atomicAdd(&gCursor[tid], cnt[tid]);
    __syncthreads();
    for (int i = tid; i < nedge; i += 256) {
        unsigned int p = pairs[i];
        int b = p >> 24;
        gbuf[(size_t)b * CAP + base[b] + (i - excl[b])] = p;
    }
}

// ---- K2: blocks < NBUCK: inline bucket-scan + per-bucket CSR build
//          blocks >= NBUCK: Whb(bf16) = x @ W^T + b (4-row register tile)
__global__ void __launch_bounds__(256) csr_wh_kernel(
    const unsigned int* __restrict__ gbuf, const int* __restrict__ gCursor,
    int* __restrict__ off, unsigned short* __restrict__ csr,
    const float* __restrict__ x, const float* __restrict__ W,
    const float* __restrict__ bias, unsigned short* __restrict__ Whb) {
    __shared__ __align__(16) char smem[20480];
    int tid = threadIdx.x;

    if (blockIdx.x < NBUCK) {
        int* s    = (int*)smem;
        int* hist = s + 256;
        int* excl = s + 512;
        int* cur  = s + 768;
        int k = blockIdx.x;
        int v = (tid < NBUCK) ? gCursor[tid] : 0;
        s[tid] = v; __syncthreads();
        for (int o = 1; o < 256; o <<= 1) {
            int t = (tid >= o) ? s[tid - o] : 0;
            __syncthreads();
            s[tid] += t;
            __syncthreads();
        }
        int base_k = (k == 0) ? 0 : s[k - 1];
        int cnt = s[k] - base_k;
        const unsigned int* bp = gbuf + (size_t)k * CAP;
        hist[tid] = 0; cur[tid] = 0;
        __syncthreads();
        for (int i = tid; i < cnt; i += 256)
            atomicAdd(&hist[(bp[i] >> 16) & 255], 1);
        __syncthreads();
        int hv = hist[tid];
        excl[tid] = hv; __syncthreads();
        for (int o = 1; o < 256; o <<= 1) {
            int t = (tid >= o) ? excl[tid - o] : 0;
            __syncthreads();
            excl[tid] += t;
            __syncthreads();
        }
        int hex = excl[tid] - hv;
        __syncthreads();
        excl[tid] = hex;
        __syncthreads();
        int dst = k * 256 + tid;
        if (dst < NN) off[dst] = base_k + hex;
        if (k == 0 && tid == 0) off[NN] = EE;
        for (int i = tid; i < cnt; i += 256) {
            unsigned int p = bp[i];
            int local = (p >> 16) & 255;
            int slot = base_k + excl[local] + atomicAdd(&cur[local], 1);
            csr[slot] = (unsigned short)(p & 0xffffu);
        }
        return;
    }

    // ---------------- wh part: 4 rows per wave-iteration ----------------
    int bid = blockIdx.x - NBUCK;
    float4* Wl = (float4*)smem;                         // 16 KB, swizzled
    float4 (*xr)[4][16] = (float4 (*)[4][16])(smem + 16384);
    const float4* W4 = (const float4*)W;
    const float4* x4 = (const float4*)x;
    for (int i = tid; i < 1024; i += 256) {
        int c = i >> 4, k4 = i & 15;
        Wl[c * 16 + (k4 ^ (c & 15))] = W4[i];
    }
    __syncthreads();
    int wv = tid >> 6, lane = tid & 63;
    int c = lane;
    float4 wreg[16];
#pragma unroll
    for (int k4 = 0; k4 < 16; ++k4) wreg[k4] = Wl[c * 16 + (k4 ^ (c & 15))];
    float bv = bias[c];
    int l16 = lane >> 4, q = lane & 15;
    for (int rowbase = (bid * 4 + wv) * 4; rowbase < NN; rowbase += WHB * 16) {
        xr[wv][l16][q] = x4[(size_t)(rowbase + l16) * 16 + q];
        float acc0 = bv, acc1 = bv, acc2 = bv, acc3 = bv;
#pragma unroll
        for (int k4 = 0; k4 < 16; ++k4) {
            float4 w  = wreg[k4];
            float4 q0 = xr[wv][0][k4];
            float4 q1 = xr[wv][1][k4];
            float4 q2 = xr[wv][2][k4];
            float4 q3 = xr[wv][3][k4];
            acc0 += w.x * q0.x + w.y * q0.y + w.z * q0.z + w.w * q0.w;
            acc1 += w.x * q1.x + w.y * q1.y + w.z * q1.z + w.w * q1.w;
            acc2 += w.x * q2.x + w.y * q2.y + w.z * q2.z + w.w * q2.w;
            acc3 += w.x * q3.x + w.y * q3.y + w.z * q3.z + w.w * q3.w;
        }
        Whb[(size_t)(rowbase + 0) * DD + c] = f2b(acc0);   // 128B/row coalesced
        Whb[(size_t)(rowbase + 1) * DD + c] = f2b(acc1);
        Whb[(size_t)(rowbase + 2) * DD + c] = f2b(acc2);
        Whb[(size_t)(rowbase + 3) * DD + c] = f2b(acc3);
    }
}

// ---- K3: fused gather + softmax + sigmoid; 8 edges/iter, 8 lanes/edge ------
// lane = (edge-slot eb = lane>>3) x (feature-octet fq = lane&7)
__global__ void __launch_bounds__(256) fused_kernel(
    const unsigned short* __restrict__ Whb, const float4* __restrict__ a4,
    const int* __restrict__ off, const unsigned short* __restrict__ csr,
    float4* __restrict__ out4) {
    int wave = threadIdx.x >> 6, lane = threadIdx.x & 63;
    int node = blockIdx.x * 4 + wave;
    int eb = lane >> 3, fq = lane & 7;
    float4 a0 = a4[fq * 2], a1 = a4[fq * 2 + 1];
    float av[8] = {a0.x, a0.y, a0.z, a0.w, a1.x, a1.y, a1.z, a1.w};
    uint4 wu = *(const uint4*)(Whb + (size_t)node * DD + fq * 8);
    float whi[8];
    unpack2(wu.x, whi[0], whi[1]); unpack2(wu.y, whi[2], whi[3]);
    unpack2(wu.z, whi[4], whi[5]); unpack2(wu.w, whi[6], whi[7]);
    int beg = off[node], end = off[node + 1];
    float den = 0.f;
    float acc[8] = {0.f, 0.f, 0.f, 0.f, 0.f, 0.f, 0.f, 0.f};
    if (beg < end) {
        int last = end - 1;
        int i0 = min(beg + eb, last);
        int i1 = min(beg + 8 + eb, last);
        uint4 p0 = *(const uint4*)(Whb + (size_t)csr[i0] * DD + fq * 8);
        uint4 p1 = *(const uint4*)(Whb + (size_t)csr[i1] * DD + fq * 8);
        for (int base = beg; base < end; base += 8) {
            uint4 u = p0;
            p0 = p1;
            int ni = min(base + 16 + eb, last);        // clamped, always valid
            p1 = *(const uint4*)(Whb + (size_t)csr[ni] * DD + fq * 8);
            float whs[8];
            unpack2(u.x, whs[0], whs[1]); unpack2(u.y, whs[2], whs[3]);
            unpack2(u.z, whs[4], whs[5]); unpack2(u.w, whs[6], whs[7]);
            float t = 0.f;
#pragma unroll
            for (int j = 0; j < 8; ++j) t += av[j] * leaky(whi[j] + whs[j]);
            t += __shfl_xor(t, 1, 64);                 // reduce 8 lanes/edge
            t += __shfl_xor(t, 2, 64);
            t += __shfl_xor(t, 4, 64);
            float ex = (base + eb < end) ? __expf(t) : 0.f;
            den += ex;
#pragma unroll
            for (int j = 0; j < 8; ++j) acc[j] += ex * whs[j];
        }
    }
    // combine the 8 edge-groups (lane bits 3,4,5)
#pragma unroll
    for (int o = 8; o <= 32; o <<= 1) {
        den += __shfl_xor(den, o, 64);
#pragma unroll
        for (int j = 0; j < 8; ++j) acc[j] += __shfl_xor(acc[j], o, 64);
    }
    if (eb == 0) {
        float id = 1.f / fmaxf(den, 1e-9f);
        float4 o0, o1;
        o0.x = 1.f / (1.f + __expf(-acc[0] * id));
        o0.y = 1.f / (1.f + __expf(-acc[1] * id));
        o0.z = 1.f / (1.f + __expf(-acc[2] * id));
        o0.w = 1.f / (1.f + __expf(-acc[3] * id));
        o1.x = 1.f / (1.f + __expf(-acc[4] * id));
        o1.y = 1.f / (1.f + __expf(-acc[5] * id));
        o1.z = 1.f / (1.f + __expf(-acc[6] * id));
        o1.w = 1.f / (1.f + __expf(-acc[7] * id));
        out4[(size_t)node * 16 + fq * 2]     = o0;     // lanes 0-7: 256B/row
        out4[(size_t)node * 16 + fq * 2 + 1] = o1;
    }
}

extern "C" void kernel_launch(void* const* d_in, const int* in_sizes, int n_in,
                              void* d_out, int out_size, void* d_ws, size_t ws_size,
                              hipStream_t stream) {
    const float* x = (const float*)d_in[0];
    const float* W = (const float*)d_in[1];
    const float* b = (const float*)d_in[2];
    const float* a = (const float*)d_in[3];
    const int*   ei = (const int*)d_in[4];
    float* out = (float*)d_out;

    char* ws = (char*)d_ws;
    unsigned short* Whb     = (unsigned short*)(ws);           // 6,400,000 B
    int*            gCursor = (int*)(ws + 6400000);            // 1,024 B
    int*            off     = (int*)(ws + 6401024);            // 200,004 B
    unsigned int*   gbuf    = (unsigned int*)(ws + 6601216);   // 3,612,672 B
    unsigned short* csr     = (unsigned short*)(ws + 10213888);// 1,600,000 B

    hipMemsetAsync(gCursor, 0, 1024, stream);
    bin_kernel<<<BINB, 256, 0, stream>>>(ei, gbuf, gCursor);
    csr_wh_kernel<<<NBUCK + WHB, 256, 0, stream>>>(gbuf, gCursor, off, csr,
                                                   x, W, b, Whb);
    fused_kernel<<<NN / 4, 256, 0, stream>>>(Whb, (const float4*)a, off, csr,
                                             (float4*)out);
}